// Round 1
// baseline (504.985 us; speedup 1.0000x reference)
//
#include <hip/hip_runtime.h>

// SparseEmbedding forward: out[(b,h), :] = weight[idx[(b,h)], :]
// NE = 1,000,000 rows, C = 64 floats/row (256 B), NROWS_OUT = 4096*50 = 204,800.
//
// Strategy: 16 threads per output row, each thread copies one float4 (16 B).
// One wave64 moves 4 rows = 1 KiB. Output writes fully coalesced; each
// gathered row is a 256 B contiguous segment (DRAM-burst friendly).

__global__ __launch_bounds__(256) void SparseEmbedding_69011534512743_kernel(
    const int* __restrict__ indices,     // NROWS entries
    const float4* __restrict__ weight,   // NE * 16 float4 per row
    float4* __restrict__ out,            // NROWS * 16 float4 per row
    int nrows)
{
    const int tid   = blockIdx.x * blockDim.x + threadIdx.x;
    const int row   = tid >> 4;       // which output row
    const int chunk = tid & 15;       // which float4 within the 256 B row
    if (row < nrows) {
        const int r = indices[row];
        out[(size_t)row * 16 + chunk] = weight[(size_t)r * 16 + chunk];
    }
}

extern "C" void kernel_launch(void* const* d_in, const int* in_sizes, int n_in,
                              void* d_out, int out_size, void* d_ws, size_t ws_size,
                              hipStream_t stream) {
    const int*    indices = (const int*)d_in[0];     // (B*H,) int
    const float4* weight  = (const float4*)d_in[1];  // (NE, C) float32, C=64 -> 16 float4
    float4*       out     = (float4*)d_out;          // (B*H, C) float32

    const int nrows = in_sizes[0];                   // 204,800
    const int total_threads = nrows * 16;
    const int block = 256;
    const int grid  = (total_threads + block - 1) / block;

    SparseEmbedding_69011534512743_kernel<<<grid, block, 0, stream>>>(
        indices, weight, out, nrows);
}